// Round 13
// baseline (129.381 us; speedup 1.0000x reference)
//
#include <hip/hip_runtime.h>

typedef _Float16 half2v __attribute__((ext_vector_type(2)));
typedef _Float16 half4v __attribute__((ext_vector_type(4)));
typedef _Float16 half8v __attribute__((ext_vector_type(8)));
typedef float f32x4 __attribute__((ext_vector_type(4)));

// ---- fused front-end: dw3x3 (VALU) + pw1x1/red1x1 (MFMA) + BN partials ----
// (R6-verified, unchanged) 8x8 px tile, 1024 blocks (4/CU), 4 waves.
__launch_bounds__(256, 4)
__global__ void k_front(const float* __restrict__ in, const float* __restrict__ wdw,
                        const float* __restrict__ wpw, const float* __restrict__ wred,
                        _Float16* __restrict__ h16, _Float16* __restrict__ r16,
                        float* __restrict__ partial){
  __shared__ float4 s_in4[4][10][12];              // [wave][ry][rx] 4ch contiguous
  __shared__ __attribute__((aligned(16))) _Float16 s_dwh[64][72];  // [px][c]
  __shared__ __attribute__((aligned(16))) _Float16 s_cvh[64][72];  // [px][c]
  __shared__ float s_red[4][32];
  int t = threadIdx.x;
  int w = t >> 6, lane = t & 63;
  int lx = lane & 7, ly = lane >> 3;
  int c15 = lane & 15, hi = lane >> 4;
  int blk0 = blockIdx.x;

  int blk = ((blk0 & 7) << 7) | (blk0 >> 3);       // XCD-contiguous remap (bijective)
  int tile = blk & 255, b = blk >> 8;
  int x0 = (tile & 15) << 3, y0 = (tile >> 4) << 3;
  const float* inb = in + ((long)b << 20) + ((long)(w << 2) << 14);

  // ---- A-fragments loaded once: pw rows 16w..16w+15, red rows 0..15 ----
  const float* ap = wpw + (((w << 4) + c15) << 6) + (hi << 3);
  float4 ap0 = *(const float4*)(ap);
  float4 ap1 = *(const float4*)(ap + 4);
  float4 ap2 = *(const float4*)(ap + 32);
  float4 ap3 = *(const float4*)(ap + 36);
  const float* arp = wred + (c15 << 6) + (hi << 3);
  float4 ar0 = *(const float4*)(arp);
  float4 ar1 = *(const float4*)(arp + 4);
  float4 ar2 = *(const float4*)(arp + 32);
  float4 ar3 = *(const float4*)(arp + 36);
  half8v a_pw0 = {(_Float16)ap0.x,(_Float16)ap0.y,(_Float16)ap0.z,(_Float16)ap0.w,
                  (_Float16)ap1.x,(_Float16)ap1.y,(_Float16)ap1.z,(_Float16)ap1.w};
  half8v a_pw1 = {(_Float16)ap2.x,(_Float16)ap2.y,(_Float16)ap2.z,(_Float16)ap2.w,
                  (_Float16)ap3.x,(_Float16)ap3.y,(_Float16)ap3.z,(_Float16)ap3.w};
  half8v a_rd0 = {(_Float16)ar0.x,(_Float16)ar0.y,(_Float16)ar0.z,(_Float16)ar0.w,
                  (_Float16)ar1.x,(_Float16)ar1.y,(_Float16)ar1.z,(_Float16)ar1.w};
  half8v a_rd1 = {(_Float16)ar2.x,(_Float16)ar2.y,(_Float16)ar2.z,(_Float16)ar2.w,
                  (_Float16)ar3.x,(_Float16)ar3.y,(_Float16)ar3.z,(_Float16)ar3.w};

  // ---- per-wave halo staging: wave w owns channel group w; 100 pts, 2/lane ----
  int p1 = lane + 64;
  int ry0 = lane / 10, rx0 = lane - ry0 * 10;
  int ry1 = p1 / 10,   rx1 = p1 - ry1 * 10;
  int yy0 = y0 + ry0 - 1, xx0 = x0 + rx0 - 1;
  int yy1 = y0 + ry1 - 1, xx1 = x0 + rx1 - 1;
  bool ok0 = (unsigned)yy0 < 128u && (unsigned)xx0 < 128u;
  bool ok1 = (p1 < 100) && ((unsigned)yy1 < 128u) && ((unsigned)xx1 < 128u);
  int o0 = (yy0 << 7) + xx0, o1 = (yy1 << 7) + xx1;

  auto dw_dep = [&](int q){
    int wdbase = __builtin_amdgcn_readfirstlane(((q << 4) + (w << 2)) * 9);
    const float* wd = wdw + wdbase;                // forced scalar path
    float4 a = make_float4(0.f,0.f,0.f,0.f);
    float4 cv = make_float4(0.f,0.f,0.f,0.f);
    #pragma unroll
    for (int dy = 0; dy < 3; dy++){
      #pragma unroll
      for (int dx = 0; dx < 3; dx++){
        float4 v = s_in4[w][ly + dy][lx + dx];
        int k = dy * 3 + dx;
        a.x += v.x * wd[k];
        a.y += v.y * wd[9 + k];
        a.z += v.z * wd[18 + k];
        a.w += v.w * wd[27 + k];
        if (k == 4) cv = v;
      }
    }
    int cb = (q << 4) + (w << 2);
    half4v ah = {(_Float16)a.x,(_Float16)a.y,(_Float16)a.z,(_Float16)a.w};
    half4v eh = {(_Float16)cv.x,(_Float16)cv.y,(_Float16)cv.z,(_Float16)cv.w};
    *(half4v*)&s_dwh[lane][cb] = ah;
    *(half4v*)&s_cvh[lane][cb] = eh;
  };

  // 2-deep prologue: q=0 -> buffer A, q=1 -> buffer B
  float4 vA0 = make_float4(0.f,0.f,0.f,0.f), vA1 = vA0, vB0 = vA0, vB1 = vA0;
  if (ok0){ vA0.x = inb[o0]; vA0.y = inb[o0+16384]; vA0.z = inb[o0+32768]; vA0.w = inb[o0+49152]; }
  if (ok1){ vA1.x = inb[o1]; vA1.y = inb[o1+16384]; vA1.z = inb[o1+32768]; vA1.w = inb[o1+49152]; }
  {
    const float* p1q = inb + (1L << 18);
    if (ok0){ vB0.x = p1q[o0]; vB0.y = p1q[o0+16384]; vB0.z = p1q[o0+32768]; vB0.w = p1q[o0+49152]; }
    if (ok1){ vB1.x = p1q[o1]; vB1.y = p1q[o1+16384]; vB1.z = p1q[o1+32768]; vB1.w = p1q[o1+49152]; }
  }

  #pragma unroll
  for (int qq = 0; qq < 2; qq++){
    s_in4[w][ry0][rx0] = vA0;
    if (p1 < 100) s_in4[w][ry1][rx1] = vA1;
    __builtin_amdgcn_wave_barrier();
    if (qq == 0){
      const float* pq = inb + (2L << 18);
      vA0 = make_float4(0.f,0.f,0.f,0.f); vA1 = vA0;
      if (ok0){ vA0.x = pq[o0]; vA0.y = pq[o0+16384]; vA0.z = pq[o0+32768]; vA0.w = pq[o0+49152]; }
      if (ok1){ vA1.x = pq[o1]; vA1.y = pq[o1+16384]; vA1.z = pq[o1+32768]; vA1.w = pq[o1+49152]; }
    }
    dw_dep(qq << 1);
    __builtin_amdgcn_wave_barrier();

    s_in4[w][ry0][rx0] = vB0;
    if (p1 < 100) s_in4[w][ry1][rx1] = vB1;
    __builtin_amdgcn_wave_barrier();
    if (qq == 0){
      const float* pq = inb + (3L << 18);
      vB0 = make_float4(0.f,0.f,0.f,0.f); vB1 = vB0;
      if (ok0){ vB0.x = pq[o0]; vB0.y = pq[o0+16384]; vB0.z = pq[o0+32768]; vB0.w = pq[o0+49152]; }
      if (ok1){ vB1.x = pq[o1]; vB1.y = pq[o1+16384]; vB1.z = pq[o1+32768]; vB1.w = pq[o1+49152]; }
    }
    dw_dep((qq << 1) + 1);
    __builtin_amdgcn_wave_barrier();
  }

  __syncthreads();                                 // all 64 channels deposited

  // ---- pw GEMM: wave w -> o-rows 16w..16w+15, 64 px, K=64 (8 MFMAs) ----
  f32x4 z = {0.f,0.f,0.f,0.f};
  f32x4 acc[4] = {z, z, z, z};
  #pragma unroll
  for (int tt = 0; tt < 4; tt++){
    half8v b0 = *(const half8v*)&s_dwh[(tt << 4) + c15][hi << 3];
    half8v b1 = *(const half8v*)&s_dwh[(tt << 4) + c15][32 + (hi << 3)];
    acc[tt] = __builtin_amdgcn_mfma_f32_16x16x32_f16(a_pw0, b0, acc[tt], 0, 0, 0);
    acc[tt] = __builtin_amdgcn_mfma_f32_16x16x32_f16(a_pw1, b1, acc[tt], 0, 0, 0);
  }
  #pragma unroll
  for (int tt = 0; tt < 4; tt++){
    int px = (tt << 4) + c15;
    int pyl = px >> 3, pxl = px & 7;
    int gout = (w << 2) + hi;
    long off = ((((long)((b << 4) + gout)) << 14) + ((y0 + pyl) << 7) + x0 + pxl) << 2;
    half4v hv = {(_Float16)acc[tt][0], (_Float16)acc[tt][1],
                 (_Float16)acc[tt][2], (_Float16)acc[tt][3]};
    *(half4v*)&h16[off] = hv;
  }

  // ---- red GEMM: wave w -> px-tile w (16 ch x 16 px, K=64) = 2 MFMAs ----
  f32x4 rac = z;
  {
    half8v b0 = *(const half8v*)&s_cvh[(w << 4) + c15][hi << 3];
    half8v b1 = *(const half8v*)&s_cvh[(w << 4) + c15][32 + (hi << 3)];
    rac = __builtin_amdgcn_mfma_f32_16x16x32_f16(a_rd0, b0, rac, 0, 0, 0);
    rac = __builtin_amdgcn_mfma_f32_16x16x32_f16(a_rd1, b1, rac, 0, 0, 0);
  }
  {
    int px = (w << 4) + c15;
    int pyl = px >> 3, pxl = px & 7;
    long roff = ((((long)b << 14) + ((y0 + pyl) << 7) + x0 + pxl) << 4) + (hi << 2);
    half4v rv4 = {(_Float16)rac[0], (_Float16)rac[1], (_Float16)rac[2], (_Float16)rac[3]};
    *(half4v*)&r16[roff] = rv4;
  }

  // ---- BN partials: wave-reduce over 16 px, combine waves, ONE 128B store ----
  #pragma unroll
  for (int rr = 0; rr < 4; rr++){
    float v = rac[rr], s2 = v * v;
    #pragma unroll
    for (int m = 1; m < 16; m <<= 1){
      v  += __shfl_xor(v,  m, 64);
      s2 += __shfl_xor(s2, m, 64);
    }
    if (c15 == 0){
      int ch = (hi << 2) + rr;
      s_red[w][2 * ch]     = v;
      s_red[w][2 * ch + 1] = s2;
    }
  }
  __syncthreads();
  if (t < 32)
    partial[(blk0 << 5) + t] = s_red[0][t] + s_red[1][t] + s_red[2][t] + s_red[3][t];
}

// ---- reduce 1024 BN partial slots -> sb[32]; w_span -> fp16 (+zero pad) ----
__global__ void k_red(const float* __restrict__ partial, const float* __restrict__ gamma,
                      const float* __restrict__ beta, float* __restrict__ sb,
                      const float* __restrict__ wspan, _Float16* __restrict__ w16){
  __shared__ float sp[1024];
  int t = threadIdx.x;
  int c = t & 31, grp = t >> 5;                    // 32 groups x 32 stat-slots
  float s = 0.f;
  #pragma unroll 4
  for (int i = grp; i < 1024; i += 32) s += partial[(i << 5) + c];
  sp[t] = s;
  for (int i = t; i < 12544; i += 1024) w16[i] = (_Float16)wspan[i];
  for (int i = 12544 + t; i < 16384; i += 1024) w16[i] = (_Float16)0.f;  // pad for rt=3 A-frags
  __syncthreads();
  if (t < 32){
    float v = 0.f;
    #pragma unroll
    for (int k = 0; k < 32; k++) v += sp[(k << 5) + t];
    sp[t] = v;                                     // columns disjoint -> safe
  }
  __syncthreads();
  if (t < 16){
    const float inv_n = 1.52587890625e-5f;         // 1/65536 (exact)
    float mean = sp[2 * t] * inv_n;
    float var  = sp[2 * t + 1] * inv_n - mean * mean;
    float inv  = rsqrtf(var + 1e-5f);
    float sc   = gamma[t] * inv;
    sb[2 * t]     = sc;
    sb[2 * t + 1] = beta[t] - mean * sc;
  }
}

// ---- main involution v6: MFMA kern-gen ----
// k_main was VALU-issue-bound (~650 instr/thread, ~33us). The 392 fdot2 of
// kern-gen (kv[49] = rv[16]·wg[49x16]) move to the matrix pipe: per wave a
// 64tap x 64px x K16(pad32) GEMM = 16 mfma_f32_16x16x32_f16 using the SAME
// fragment pattern as k_front's pw GEMM (A[row=c15][k=8hi+j], B[col=c15][...],
// D[col=c15][row=4hi+r] — verified here since R2). D-frags land in s_kv[px][k]
// (f32, exact); each thread reads back its own row. Wave-local LDS handoff
// (R6-verified pattern) -> still ONE __syncthreads total.
__launch_bounds__(256)
__global__ void k_main(const _Float16* __restrict__ h16, const _Float16* __restrict__ r16,
                       const float* __restrict__ sb, const _Float16* __restrict__ w16,
                       float* __restrict__ out){
  __shared__ float4 s_h4[22][25];                  // halo [row][col+pad] fp32
  __shared__ float  s_sb[32];
  __shared__ __attribute__((aligned(16))) _Float16 s_rv[258][16];   // [px][c]
  __shared__ __attribute__((aligned(16))) float    s_kv[256][52];   // [px][tap]
  int t = threadIdx.x;
  int g = blockIdx.y, b = blockIdx.z;
  int bx = blockIdx.x;
  bx = ((bx & 7) << 3) | (bx >> 3);                // XCD-contiguous remap (bijective)
  int tx0 = (bx & 7) << 4, ty0 = (bx >> 3) << 4;

  int ltx = t & 15, lty = t >> 4;
  int px = tx0 + ltx, py = ty0 + lty;
  int lane = t & 63, w = t >> 6, c15 = lane & 15, hi = lane >> 4;

  // r: all 16 channels contiguous -> 2x16B loads, issued early
  const _Float16* rp = r16 + ((((long)b << 14) + (py << 7) + px) << 4);
  half8v ra = *(const half8v*)rp;
  half8v rb = *(const half8v*)(rp + 8);

  // h halo: one 8B half4 load per point (4 cg channels contiguous)
  const _Float16* hp = h16 + (((long)((b << 4) + g)) << 16);
  for (int p = t; p < 484; p += 256){              // 22x22 halo points
    int ry = p / 22, rx = p - ry * 22;
    int yy = ty0 + ry - 3, xx = tx0 + rx - 3;
    float4 v = make_float4(0.f,0.f,0.f,0.f);
    if ((unsigned)yy < 128u && (unsigned)xx < 128u){
      half4v hh = *(const half4v*)&hp[(long)(((yy << 7) + xx) << 2)];
      v = make_float4((float)hh[0], (float)hh[1], (float)hh[2], (float)hh[3]);
    }
    s_h4[ry][rx] = v;
  }
  if (t < 32) s_sb[t] = sb[t];
  __syncthreads();

  // BN + ReLU; pack rv fp16 into s_rv[t] (own px row)
  float rv[16];
  #pragma unroll
  for (int c = 0; c < 8; c++){
    rv[c]     = fmaxf((float)ra[c] * s_sb[2*c]     + s_sb[2*c+1],     0.f);
    rv[c + 8] = fmaxf((float)rb[c] * s_sb[2*(c+8)] + s_sb[2*(c+8)+1], 0.f);
  }
  half8v rv_lo = {(_Float16)rv[0], (_Float16)rv[1], (_Float16)rv[2], (_Float16)rv[3],
                  (_Float16)rv[4], (_Float16)rv[5], (_Float16)rv[6], (_Float16)rv[7]};
  half8v rv_hi = {(_Float16)rv[8], (_Float16)rv[9], (_Float16)rv[10],(_Float16)rv[11],
                  (_Float16)rv[12],(_Float16)rv[13],(_Float16)rv[14],(_Float16)rv[15]};
  *(half8v*)&s_rv[t][0] = rv_lo;
  *(half8v*)&s_rv[t][8] = rv_hi;
  __builtin_amdgcn_wave_barrier();                 // in-wave write->read (R6 pattern)

  // kern-gen: wave w computes kv[taps 0..63][its 64 px] = 16 MFMAs, K=16 pad 32
  const _Float16* wgg = w16 + g * 784;
  f32x4 z = {0.f, 0.f, 0.f, 0.f};
  int pbase = (w << 6) + c15;
  int bco = (hi < 2) ? (hi << 3) : 0;              // B k-cols; hi>=2 masked via A=0
  #pragma unroll
  for (int rt = 0; rt < 4; rt++){
    half8v a = {0,0,0,0,0,0,0,0};
    if (hi < 2)                                    // A[tap=16rt+c15][c=8hi+j]
      a = *(const half8v*)&wgg[(rt << 8) + (c15 << 4) + (hi << 3)];
    #pragma unroll
    for (int ct = 0; ct < 4; ct++){
      half8v bf = *(const half8v*)&s_rv[pbase + (ct << 4)][bco];
      f32x4 d = __builtin_amdgcn_mfma_f32_16x16x32_f16(a, bf, z, 0, 0, 0);
      if (rt < 3 || hi == 0)                       // taps >=52 unused; keep [52] cols
        *(f32x4*)&s_kv[pbase + (ct << 4)][(rt << 4) + (hi << 2)] = d;
    }
  }
  __builtin_amdgcn_wave_barrier();                 // in-wave write->read

  // own kv row back to registers (taps 0..48 used; compile-time indexed)
  float kv[52];
  #pragma unroll
  for (int j = 0; j < 13; j++)
    *(f32x4*)&kv[j << 2] = *(const f32x4*)&s_kv[t][j << 2];

  float acc0 = 0.f, acc1 = 0.f, acc2 = 0.f, acc3 = 0.f;
  #pragma unroll
  for (int kh = 0; kh < 7; kh++){
    #pragma unroll
    for (int kw = 0; kw < 7; kw++){
      float kvv = kv[kh * 7 + kw];
      float4 hv = s_h4[lty + kh][ltx + kw];
      acc0 += kvv * hv.x;
      acc1 += kvv * hv.y;
      acc2 += kvv * hv.z;
      acc3 += kvv * hv.w;
    }
  }

  long obase = (((long)((b << 6) + (g << 2))) << 14) + (py << 7) + px;
  out[obase]         = acc0;
  out[obase + 16384] = acc1;
  out[obase + 32768] = acc2;
  out[obase + 49152] = acc3;
}

extern "C" void kernel_launch(void* const* d_in, const int* in_sizes, int n_in,
                              void* d_out, int out_size, void* d_ws, size_t ws_size,
                              hipStream_t stream){
  const float* in       = (const float*)d_in[0];
  const float* w_dw     = (const float*)d_in[1];
  const float* w_pw     = (const float*)d_in[2];
  const float* gamma    = (const float*)d_in[3];
  const float* beta     = (const float*)d_in[4];
  const float* w_reduce = (const float*)d_in[5];
  const float* w_span   = (const float*)d_in[6];
  float* out = (float*)d_out;

  _Float16* h16 = (_Float16*)d_ws;                 // 4194304 halfs (8 MB)
  _Float16* r16 = h16 + 4194304;                   // 1048576 halfs (2 MB)
  _Float16* w16 = r16 + 1048576;                   // 12544 halfs (padded to 16384)
  float* partial = (float*)(w16 + 16384);          // 1024*32 floats (128 KB)
  float* sb      = partial + 32768;                // 32 floats

  k_front<<<1024, 256, 0, stream>>>(in, w_dw, w_pw, w_reduce, h16, r16, partial);
  k_red  <<<1, 1024, 0, stream>>>(partial, gamma, beta, sb, w_span, w16);
  dim3 grid(64, 16, 4);
  k_main <<<grid, 256, 0, stream>>>(h16, r16, sb, w16, out);
}

// Round 14
// 121.476 us; speedup vs baseline: 1.0651x; 1.0651x over previous
//
#include <hip/hip_runtime.h>

typedef _Float16 half2v __attribute__((ext_vector_type(2)));
typedef _Float16 half4v __attribute__((ext_vector_type(4)));
typedef _Float16 half8v __attribute__((ext_vector_type(8)));
typedef float f32x4 __attribute__((ext_vector_type(4)));

// ---- fused front-end: dw3x3 (VALU) + pw1x1/red1x1 (MFMA) + BN partials ----
// 8x8 px tile, 1024 blocks (4/CU), 4 waves. q-loop barrier-free (wave-private
// s_in4[w]). NEW (R14): 4-DEEP prefetch — all 4 q-chunks' global loads issue
// in the prologue (32 dwords/thread in flight); each commit's ds_write waits
// (via compiler vmcnt) only for its own buffer -> one exposed HBM latency
// instead of four. +16 VGPR (~80 total, 4 waves/SIMD preserved).
__launch_bounds__(256, 4)
__global__ void k_front(const float* __restrict__ in, const float* __restrict__ wdw,
                        const float* __restrict__ wpw, const float* __restrict__ wred,
                        _Float16* __restrict__ h16, _Float16* __restrict__ r16,
                        float* __restrict__ partial){
  __shared__ float4 s_in4[4][10][12];              // [wave][ry][rx] 4ch contiguous
  __shared__ __attribute__((aligned(16))) _Float16 s_dwh[64][72];  // [px][c]
  __shared__ __attribute__((aligned(16))) _Float16 s_cvh[64][72];  // [px][c]
  __shared__ float s_red[4][32];
  int t = threadIdx.x;
  int w = t >> 6, lane = t & 63;
  int lx = lane & 7, ly = lane >> 3;
  int c15 = lane & 15, hi = lane >> 4;
  int blk0 = blockIdx.x;

  int blk = ((blk0 & 7) << 7) | (blk0 >> 3);       // XCD-contiguous remap (bijective)
  int tile = blk & 255, b = blk >> 8;
  int x0 = (tile & 15) << 3, y0 = (tile >> 4) << 3;
  const float* inb = in + ((long)b << 20) + ((long)(w << 2) << 14);

  // ---- per-wave halo staging geometry: wave w owns channel group w ----
  int p1 = lane + 64;
  int ry0 = lane / 10, rx0 = lane - ry0 * 10;
  int ry1 = p1 / 10,   rx1 = p1 - ry1 * 10;
  int yy0 = y0 + ry0 - 1, xx0 = x0 + rx0 - 1;
  int yy1 = y0 + ry1 - 1, xx1 = x0 + rx1 - 1;
  bool ok0 = (unsigned)yy0 < 128u && (unsigned)xx0 < 128u;
  bool ok1 = (p1 < 100) && ((unsigned)yy1 < 128u) && ((unsigned)xx1 < 128u);
  int o0 = (yy0 << 7) + xx0, o1 = (yy1 << 7) + xx1;

  // ---- 4-deep prologue: ALL q-chunk loads issued now ----
  float4 vb0[4], vb1[4];
  #pragma unroll
  for (int q = 0; q < 4; q++){
    const float* pq = inb + ((long)q << 18);
    float4 a = make_float4(0.f,0.f,0.f,0.f), bb = a;
    if (ok0){ a.x  = pq[o0]; a.y  = pq[o0+16384]; a.z  = pq[o0+32768]; a.w  = pq[o0+49152]; }
    if (ok1){ bb.x = pq[o1]; bb.y = pq[o1+16384]; bb.z = pq[o1+32768]; bb.w = pq[o1+49152]; }
    vb0[q] = a; vb1[q] = bb;
  }

  // ---- A-fragments (loaded once; issue after staging loads) ----
  const float* ap = wpw + (((w << 4) + c15) << 6) + (hi << 3);
  float4 ap0 = *(const float4*)(ap);
  float4 ap1 = *(const float4*)(ap + 4);
  float4 ap2 = *(const float4*)(ap + 32);
  float4 ap3 = *(const float4*)(ap + 36);
  const float* arp = wred + (c15 << 6) + (hi << 3);
  float4 ar0 = *(const float4*)(arp);
  float4 ar1 = *(const float4*)(arp + 4);
  float4 ar2 = *(const float4*)(arp + 32);
  float4 ar3 = *(const float4*)(arp + 36);
  half8v a_pw0 = {(_Float16)ap0.x,(_Float16)ap0.y,(_Float16)ap0.z,(_Float16)ap0.w,
                  (_Float16)ap1.x,(_Float16)ap1.y,(_Float16)ap1.z,(_Float16)ap1.w};
  half8v a_pw1 = {(_Float16)ap2.x,(_Float16)ap2.y,(_Float16)ap2.z,(_Float16)ap2.w,
                  (_Float16)ap3.x,(_Float16)ap3.y,(_Float16)ap3.z,(_Float16)ap3.w};
  half8v a_rd0 = {(_Float16)ar0.x,(_Float16)ar0.y,(_Float16)ar0.z,(_Float16)ar0.w,
                  (_Float16)ar1.x,(_Float16)ar1.y,(_Float16)ar1.z,(_Float16)ar1.w};
  half8v a_rd1 = {(_Float16)ar2.x,(_Float16)ar2.y,(_Float16)ar2.z,(_Float16)ar2.w,
                  (_Float16)ar3.x,(_Float16)ar3.y,(_Float16)ar3.z,(_Float16)ar3.w};

  // ---- q phases: commit (waits own buffer only) -> dw conv -> deposit ----
  #pragma unroll
  for (int q = 0; q < 4; q++){
    s_in4[w][ry0][rx0] = vb0[q];
    if (p1 < 100) s_in4[w][ry1][rx1] = vb1[q];
    __builtin_amdgcn_wave_barrier();               // keep dw reads after writes

    int wdbase = __builtin_amdgcn_readfirstlane(((q << 4) + (w << 2)) * 9);
    const float* wd = wdw + wdbase;                // forced scalar path
    float4 a = make_float4(0.f,0.f,0.f,0.f);
    float4 cv = make_float4(0.f,0.f,0.f,0.f);
    #pragma unroll
    for (int dy = 0; dy < 3; dy++){
      #pragma unroll
      for (int dx = 0; dx < 3; dx++){
        float4 v = s_in4[w][ly + dy][lx + dx];
        int k = dy * 3 + dx;
        a.x += v.x * wd[k];
        a.y += v.y * wd[9 + k];
        a.z += v.z * wd[18 + k];
        a.w += v.w * wd[27 + k];
        if (k == 4) cv = v;
      }
    }
    int cb = (q << 4) + (w << 2);
    half4v ah = {(_Float16)a.x,(_Float16)a.y,(_Float16)a.z,(_Float16)a.w};
    half4v eh = {(_Float16)cv.x,(_Float16)cv.y,(_Float16)cv.z,(_Float16)cv.w};
    *(half4v*)&s_dwh[lane][cb] = ah;
    *(half4v*)&s_cvh[lane][cb] = eh;
    __builtin_amdgcn_wave_barrier();               // deposit before next commit
  }

  __syncthreads();                                 // all 64 channels deposited

  // ---- pw GEMM: wave w -> o-rows 16w..16w+15, 64 px, K=64 (8 MFMAs) ----
  f32x4 z = {0.f,0.f,0.f,0.f};
  f32x4 acc[4] = {z, z, z, z};
  #pragma unroll
  for (int tt = 0; tt < 4; tt++){
    half8v b0 = *(const half8v*)&s_dwh[(tt << 4) + c15][hi << 3];
    half8v b1 = *(const half8v*)&s_dwh[(tt << 4) + c15][32 + (hi << 3)];
    acc[tt] = __builtin_amdgcn_mfma_f32_16x16x32_f16(a_pw0, b0, acc[tt], 0, 0, 0);
    acc[tt] = __builtin_amdgcn_mfma_f32_16x16x32_f16(a_pw1, b1, acc[tt], 0, 0, 0);
  }
  #pragma unroll
  for (int tt = 0; tt < 4; tt++){
    int px = (tt << 4) + c15;
    int pyl = px >> 3, pxl = px & 7;
    int gout = (w << 2) + hi;
    long off = ((((long)((b << 4) + gout)) << 14) + ((y0 + pyl) << 7) + x0 + pxl) << 2;
    half4v hv = {(_Float16)acc[tt][0], (_Float16)acc[tt][1],
                 (_Float16)acc[tt][2], (_Float16)acc[tt][3]};
    *(half4v*)&h16[off] = hv;
  }

  // ---- red GEMM: wave w -> px-tile w (16 ch x 16 px, K=64) = 2 MFMAs ----
  f32x4 rac = z;
  {
    half8v b0 = *(const half8v*)&s_cvh[(w << 4) + c15][hi << 3];
    half8v b1 = *(const half8v*)&s_cvh[(w << 4) + c15][32 + (hi << 3)];
    rac = __builtin_amdgcn_mfma_f32_16x16x32_f16(a_rd0, b0, rac, 0, 0, 0);
    rac = __builtin_amdgcn_mfma_f32_16x16x32_f16(a_rd1, b1, rac, 0, 0, 0);
  }
  {
    int px = (w << 4) + c15;
    int pyl = px >> 3, pxl = px & 7;
    long roff = ((((long)b << 14) + ((y0 + pyl) << 7) + x0 + pxl) << 4) + (hi << 2);
    half4v rv4 = {(_Float16)rac[0], (_Float16)rac[1], (_Float16)rac[2], (_Float16)rac[3]};
    *(half4v*)&r16[roff] = rv4;
  }

  // ---- BN partials: wave-reduce over 16 px, combine waves, ONE 128B store ----
  #pragma unroll
  for (int rr = 0; rr < 4; rr++){
    float v = rac[rr], s2 = v * v;
    #pragma unroll
    for (int m = 1; m < 16; m <<= 1){
      v  += __shfl_xor(v,  m, 64);
      s2 += __shfl_xor(s2, m, 64);
    }
    if (c15 == 0){
      int ch = (hi << 2) + rr;
      s_red[w][2 * ch]     = v;
      s_red[w][2 * ch + 1] = s2;
    }
  }
  __syncthreads();
  if (t < 32)
    partial[(blk0 << 5) + t] = s_red[0][t] + s_red[1][t] + s_red[2][t] + s_red[3][t];
}

// ---- reduce 1024 BN partial slots -> sb[32]; also w_span fp32 -> fp16 ----
__global__ void k_red(const float* __restrict__ partial, const float* __restrict__ gamma,
                      const float* __restrict__ beta, float* __restrict__ sb,
                      const float* __restrict__ wspan, _Float16* __restrict__ w16){
  __shared__ float sp[1024];
  int t = threadIdx.x;
  int c = t & 31, grp = t >> 5;                    // 32 groups x 32 stat-slots
  float s = 0.f;
  #pragma unroll 4
  for (int i = grp; i < 1024; i += 32) s += partial[(i << 5) + c];
  sp[t] = s;
  for (int i = t; i < 12544; i += 1024) w16[i] = (_Float16)wspan[i];
  __syncthreads();
  if (t < 32){
    float v = 0.f;
    #pragma unroll
    for (int k = 0; k < 32; k++) v += sp[(k << 5) + t];
    sp[t] = v;                                     // columns disjoint -> safe
  }
  __syncthreads();
  if (t < 16){
    const float inv_n = 1.52587890625e-5f;         // 1/65536 (exact)
    float mean = sp[2 * t] * inv_n;
    float var  = sp[2 * t + 1] * inv_n - mean * mean;
    float inv  = rsqrtf(var + 1e-5f);
    float sc   = gamma[t] * inv;
    sb[2 * t]     = sc;
    sb[2 * t + 1] = beta[t] - mean * sc;
  }
}

// ---- main involution: ONE-WAVE blocks (8x8 px tile), no __syncthreads ----
// (R12-verified best: 64-thr blocks, 14x14 halo, wave-internal DS ordering)
__launch_bounds__(64, 4)
__global__ void k_main(const _Float16* __restrict__ h16, const _Float16* __restrict__ r16,
                       const float* __restrict__ sb, const _Float16* __restrict__ w16,
                       float* __restrict__ out){
  __shared__ float4 s_h4[14][15];                  // 8+6 halo, padded col
  int lane = threadIdx.x;
  int g = blockIdx.y, b = blockIdx.z;
  int bx = blockIdx.x;
  bx = ((bx & 7) << 5) | (bx >> 3);                // XCD-contiguous remap (256=8*32)
  int tx0 = (bx & 15) << 3, ty0 = (bx >> 4) << 3;
  int ltx = lane & 7, lty = lane >> 3;
  int px = tx0 + ltx, py = ty0 + lty;

  // r: all 16 channels contiguous -> 2x16B loads, issued first
  const _Float16* rp = r16 + ((((long)b << 14) + (py << 7) + px) << 4);
  half8v ra = *(const half8v*)rp;
  half8v rb = *(const half8v*)(rp + 8);

  // halo: 14x14 = 196 points, 4 conditional 8B loads per lane
  const _Float16* hp = h16 + (((long)((b << 4) + g)) << 16);
  #pragma unroll
  for (int i = 0; i < 4; i++){
    int p = lane + (i << 6);
    if (p < 196){
      int ry = p / 14, rx = p - ry * 14;
      int yy = ty0 + ry - 3, xx = tx0 + rx - 3;
      float4 v = make_float4(0.f,0.f,0.f,0.f);
      if ((unsigned)yy < 128u && (unsigned)xx < 128u){
        half4v hh = *(const half4v*)&hp[(long)(((yy << 7) + xx) << 2)];
        v = make_float4((float)hh[0], (float)hh[1], (float)hh[2], (float)hh[3]);
      }
      s_h4[ry][rx] = v;
    }
  }
  __builtin_amdgcn_wave_barrier();                 // writes before reads (in-wave)

  // BN scale/bias: wave-uniform kernel arg -> scalar loads (no LDS round-trip)
  float rv[16];
  #pragma unroll
  for (int c = 0; c < 8; c++){
    rv[c]     = fmaxf((float)ra[c] * sb[2*c]     + sb[2*c+1],     0.f);
    rv[c + 8] = fmaxf((float)rb[c] * sb[2*(c+8)] + sb[2*(c+8)+1], 0.f);
  }
#if __has_builtin(__builtin_amdgcn_fdot2)
  half2v rv2[8];
  #pragma unroll
  for (int j = 0; j < 8; j++){
    half2v pk; pk[0] = (_Float16)rv[2*j]; pk[1] = (_Float16)rv[2*j+1];
    rv2[j] = pk;
  }
#endif

  const _Float16* wg = w16 + g * 784;              // uniform -> scalar pipe
#if __has_builtin(__builtin_amdgcn_fdot2)
  const half2v* wg2 = (const half2v*)wg;
#endif
  float acc0 = 0.f, acc1 = 0.f, acc2 = 0.f, acc3 = 0.f;
  #pragma unroll
  for (int kh = 0; kh < 7; kh++){
    #pragma unroll
    for (int kw = 0; kw < 7; kw++){
      int k = kh * 7 + kw;
      float kv0 = 0.f, kv1 = 0.f;                  // split dep chain (2x4 deep)
#if __has_builtin(__builtin_amdgcn_fdot2)
      #pragma unroll
      for (int j = 0; j < 4; j++){
        kv0 = __builtin_amdgcn_fdot2(rv2[j],     wg2[k*8 + j],     kv0, false);
        kv1 = __builtin_amdgcn_fdot2(rv2[j + 4], wg2[k*8 + j + 4], kv1, false);
      }
#else
      #pragma unroll
      for (int c = 0; c < 8; c++){
        kv0 += rv[c]     * (float)wg[k*16 + c];
        kv1 += rv[c + 8] * (float)wg[k*16 + c + 8];
      }
#endif
      float kv = kv0 + kv1;
      float4 hv = s_h4[lty + kh][ltx + kw];
      acc0 += kv * hv.x;
      acc1 += kv * hv.y;
      acc2 += kv * hv.z;
      acc3 += kv * hv.w;
    }
  }

  long obase = (((long)((b << 6) + (g << 2))) << 14) + (py << 7) + px;
  out[obase]         = acc0;
  out[obase + 16384] = acc1;
  out[obase + 32768] = acc2;
  out[obase + 49152] = acc3;
}

extern "C" void kernel_launch(void* const* d_in, const int* in_sizes, int n_in,
                              void* d_out, int out_size, void* d_ws, size_t ws_size,
                              hipStream_t stream){
  const float* in       = (const float*)d_in[0];
  const float* w_dw     = (const float*)d_in[1];
  const float* w_pw     = (const float*)d_in[2];
  const float* gamma    = (const float*)d_in[3];
  const float* beta     = (const float*)d_in[4];
  const float* w_reduce = (const float*)d_in[5];
  const float* w_span   = (const float*)d_in[6];
  float* out = (float*)d_out;

  _Float16* h16 = (_Float16*)d_ws;                 // 4194304 halfs (8 MB)
  _Float16* r16 = h16 + 4194304;                   // 1048576 halfs (2 MB)
  _Float16* w16 = r16 + 1048576;                   // 12544 halfs (pad to 16384)
  float* partial = (float*)(w16 + 16384);          // 1024*32 floats (128 KB)
  float* sb      = partial + 32768;                // 32 floats

  k_front<<<1024, 256, 0, stream>>>(in, w_dw, w_pw, w_reduce, h16, r16, partial);
  k_red  <<<1, 1024, 0, stream>>>(partial, gamma, beta, sb, w_span, w16);
  dim3 grid(256, 16, 4);
  k_main <<<grid, 64, 0, stream>>>(h16, r16, sb, w16, out);
}